// Round 11
// baseline (411.764 us; speedup 1.0000x reference)
//
#include <hip/hip_runtime.h>
#include <hip/hip_cooperative_groups.h>
#include <math.h>

namespace cg = cooperative_groups;

namespace {

constexpr int NB = 3;      // branches
constexpr int BB = 2;      // batch
constexpr int CC = 64;     // channels
constexpr int LLEN = 4096; // H*W
constexpr int DI = 128;    // inner dim
constexpr int NN = 16;     // state dim
constexpr int RR = 4;      // rank
constexpr int GG = 256;    // scan chunks
constexpr int LC = 16;     // chunk length
constexpr int NSEQ = NB * BB * DI * NN; // 12288 scan sequences
constexpr size_t SBUF = (size_t)NB * BB * DI * LLEN; // 3145728 elems per big slot

typedef _Float16 f16;
typedef __attribute__((ext_vector_type(4))) float f32x4;
typedef __attribute__((ext_vector_type(8))) short bf16x8;
typedef __attribute__((ext_vector_type(4))) _Float16 f16x4;
typedef __attribute__((ext_vector_type(8))) _Float16 f16x8;

__device__ __forceinline__ float siluf(float v) { return v / (1.f + __expf(-v)); }

__device__ __forceinline__ short cvt_bf16(float f) {
    union { float f; unsigned u; } v; v.f = f;
    unsigned r = v.u + 0x7fffu + ((v.u >> 16) & 1u);
    return (short)(r >> 16);
}
__device__ __forceinline__ unsigned pack_bf16(float lo, float hi) {
    return ((unsigned)(unsigned short)cvt_bf16(hi) << 16) | (unsigned short)cvt_bf16(lo);
}
__device__ __forceinline__ bf16x8 pack8(float4 a, float4 b) {
    bf16x8 r;
    r[0] = cvt_bf16(a.x); r[1] = cvt_bf16(a.y); r[2] = cvt_bf16(a.z); r[3] = cvt_bf16(a.w);
    r[4] = cvt_bf16(b.x); r[5] = cvt_bf16(b.y); r[6] = cvt_bf16(b.z); r[7] = cvt_bf16(b.w);
    return r;
}
__device__ __forceinline__ f16x4 to_h4(float a, float b, float c, float d) {
    f16x4 r; r[0] = (f16)a; r[1] = (f16)b; r[2] = (f16)c; r[3] = (f16)d; return r;
}
__device__ __forceinline__ float4 to_f4(f16x4 v) {
    return make_float4((float)v[0], (float)v[1], (float)v[2], (float)v[3]);
}
// f16 LDS tile [64 l][128 d]: 16B blocks (8 f16), XOR-swizzled slot (round-7 proven)
__device__ __forceinline__ int swz16(int l, int d) {
    int b = d >> 3;
    int bs = (b & 8) | ((b ^ l) & 7);
    return l * 128 + bs * 8 + (d & 7);
}

// ---------------------------------------------------------------------------
// K1 (MFMA): embed1x1 + bias + rms + projection. Outputs l-major fp16 [ib][l][d].
// grid (64 ltile, 9 jobs, 2 b), 256 threads = 4 waves.  [round-9 verbatim]
// ---------------------------------------------------------------------------
__global__ __launch_bounds__(256) void k1_embed(
    const float* __restrict__ up, const float* __restrict__ mask_,
    const float* __restrict__ fx, const float* __restrict__ fy, const float* __restrict__ fz,
    const float* __restrict__ pe_x_w, const float* __restrict__ pe_x_b, const float* __restrict__ rms_x_w,
    const float* __restrict__ pe_i_w, const float* __restrict__ pe_i_b, const float* __restrict__ rms_i_w,
    const float* __restrict__ pe_m_w, const float* __restrict__ pe_m_b, const float* __restrict__ rms_m_w,
    const float* __restrict__ in_x_w, const float* __restrict__ in_i_w, const float* __restrict__ in_m_w,
    f16* __restrict__ xc_pre, f16* __restrict__ x_act,
    f16* __restrict__ info_pre, f16* __restrict__ mk_pre)
{
    __shared__ short sE[64 * 64];   // En bf16, [l][o] with 16B-block XOR swizzle
    __shared__ float red[4][64];
    __shared__ float sscl[64];

    int lt = blockIdx.x, job = blockIdx.y, b = blockIdx.z;
    int i = job / 3, r = job % 3;
    const float *src, *pw, *pb, *rw, *iw;
    if (r == 0) {
        src = (i == 0 ? fx : (i == 1 ? fy : fz));
        pw = pe_x_w + i * 4096; pb = pe_x_b + i * 64; rw = rms_x_w + i * 64;
        iw = in_x_w + (size_t)i * 256 * 64;
    } else if (r == 1) {
        src = up;
        pw = pe_i_w + i * 4096; pb = pe_i_b + i * 64; rw = rms_i_w + i * 64;
        iw = in_i_w + (size_t)i * 128 * 64;
    } else {
        src = mask_;
        pw = pe_m_w + i * 4096; pb = pe_m_b + i * 64; rw = rms_m_w + i * 64;
        iw = in_m_w + (size_t)i * 128 * 64;
    }
    int t = threadIdx.x;
    int w = t >> 6, lane = t & 63, lo = lane & 15, hi = lane >> 4;
    int l0 = lt * 64;
    const float* Xg = src + (size_t)b * 64 * LLEN;

    // ---- MFMA #1: E = W1 @ X ----
    f32x4 acc1[4];
    #pragma unroll
    for (int nt = 0; nt < 4; ++nt) acc1[nt] = (f32x4){0.f, 0.f, 0.f, 0.f};

    #pragma unroll
    for (int ks = 0; ks < 2; ++ks) {
        const float* ap = pw + (16 * w + lo) * 64 + ks * 32 + hi * 8;
        bf16x8 a1 = pack8(*(const float4*)ap, *(const float4*)(ap + 4));
        #pragma unroll
        for (int nt = 0; nt < 4; ++nt) {
            const float* xc = Xg + (size_t)(ks * 32 + hi * 8) * LLEN + l0 + nt * 16 + lo;
            bf16x8 b1;
            #pragma unroll
            for (int j = 0; j < 8; ++j) b1[j] = cvt_bf16(xc[(size_t)j * LLEN]);
            acc1[nt] = __builtin_amdgcn_mfma_f32_16x16x32_bf16(a1, b1, acc1[nt], 0, 0, 0);
        }
    }

    // ---- bias + rms reduction ----
    float4 pbv = *(const float4*)&pb[16 * w + 4 * hi];
    float e_[4][4];
    #pragma unroll
    for (int nt = 0; nt < 4; ++nt) {
        e_[nt][0] = acc1[nt][0] + pbv.x;
        e_[nt][1] = acc1[nt][1] + pbv.y;
        e_[nt][2] = acc1[nt][2] + pbv.z;
        e_[nt][3] = acc1[nt][3] + pbv.w;
        float s = e_[nt][0] * e_[nt][0] + e_[nt][1] * e_[nt][1]
                + e_[nt][2] * e_[nt][2] + e_[nt][3] * e_[nt][3];
        s += __shfl_xor(s, 16);
        s += __shfl_xor(s, 32);
        if (lane < 16) red[w][nt * 16 + lo] = s;
    }
    __syncthreads();
    if (t < 64) {
        float s = red[0][t] + red[1][t] + red[2][t] + red[3][t];
        sscl[t] = rsqrtf(s * (1.f / 64.f) + 1e-5f);
    }
    __syncthreads();

    // ---- En -> bf16 swizzled LDS [l][o] ----
    {
        int ob = 2 * w + (hi >> 1);
        #pragma unroll
        for (int nt = 0; nt < 4; ++nt) {
            float sc = sscl[16 * nt + lo];
            unsigned p0 = pack_bf16(e_[nt][0] * sc, e_[nt][1] * sc);
            unsigned p1 = pack_bf16(e_[nt][2] * sc, e_[nt][3] * sc);
            unsigned* p = (unsigned*)&sE[(16 * nt + lo) * 64 + (ob ^ (lo & 7)) * 8 + 4 * (hi & 1)];
            p[0] = p0; p[1] = p1;
        }
    }
    __syncthreads();

    // ---- MFMA #2 ----
    bf16x8 b2[4][2];
    #pragma unroll
    for (int nt = 0; nt < 4; ++nt)
        #pragma unroll
        for (int ks = 0; ks < 2; ++ks) {
            int db = ks * 4 + hi;
            b2[nt][ks] = *(const bf16x8*)&sE[(16 * nt + lo) * 64 + (db ^ (lo & 7)) * 8];
        }

    size_t obase = ((size_t)(i * 2 + b)) * DI * LLEN;
    int MT = (r == 0) ? 4 : 2; // M-tiles per wave
    for (int mm = 0; mm < MT; ++mm) {
        int m = MT * w + mm;
        bf16x8 a2[2];
        #pragma unroll
        for (int ks = 0; ks < 2; ++ks) {
            const float* wp = iw + (size_t)(16 * m + lo) * 64 + ks * 32 + hi * 8;
            float4 w0 = *(const float4*)wp;
            float4 w1 = *(const float4*)(wp + 4);
            float4 r0 = *(const float4*)&rw[ks * 32 + hi * 8];
            float4 r1 = *(const float4*)&rw[ks * 32 + hi * 8 + 4];
            w0.x *= r0.x; w0.y *= r0.y; w0.z *= r0.z; w0.w *= r0.w;
            w1.x *= r1.x; w1.y *= r1.y; w1.z *= r1.z; w1.w *= r1.w;
            a2[ks] = pack8(w0, w1);
        }
        f32x4 acc2[4];
        #pragma unroll
        for (int nt = 0; nt < 4; ++nt) acc2[nt] = (f32x4){0.f, 0.f, 0.f, 0.f};
        #pragma unroll
        for (int ks = 0; ks < 2; ++ks)
            #pragma unroll
            for (int nt = 0; nt < 4; ++nt)
                acc2[nt] = __builtin_amdgcn_mfma_f32_16x16x32_bf16(a2[ks], b2[nt][ks], acc2[nt], 0, 0, 0);

        int d0 = 16 * m + 4 * hi;
        f16* dst; int dd = d0;
        if (r == 0) { if (d0 < 128) dst = xc_pre; else { dst = x_act; dd = d0 - 128; } }
        else if (r == 1) dst = info_pre;
        else dst = mk_pre;
        #pragma unroll
        for (int nt = 0; nt < 4; ++nt) {
            int l = l0 + 16 * nt + lo;
            *(f16x4*)&dst[obase + (size_t)l * DI + dd] =
                to_h4(acc2[nt][0], acc2[nt][1], acc2[nt][2], acc2[nt][3]);
        }
    }
}

// ---------------------------------------------------------------------------
// K3: causal dwconv(K=3)+SiLU + matvec, ONE stream per block.
// grid (64 ltile, 6 ib, 3 stream), 256 threads.  [round-9 verbatim]
// ---------------------------------------------------------------------------
__global__ __launch_bounds__(256) void k3_conv(
    const f16* __restrict__ xc_pre, const f16* __restrict__ info_pre, const f16* __restrict__ mk_pre,
    const float* __restrict__ conv_x_w, const float* __restrict__ conv_x_b,
    const float* __restrict__ conv_i_w, const float* __restrict__ conv_i_b,
    const float* __restrict__ conv_m_w, const float* __restrict__ conv_m_b,
    const float* __restrict__ delta_w, const float* __restrict__ dt_w, const float* __restrict__ dt_b,
    const float* __restrict__ B_w, const float* __restrict__ C_w,
    f16* __restrict__ u, f16* __restrict__ delta,
    f16* __restrict__ Bm, f16* __restrict__ Cm)
{
    __shared__ __align__(16) f16 ot[64 * 128]; // [l][d] swz16, 16 KB
    __shared__ float rvec[4 * 64];             // [r][l]

    int lt = blockIdx.x, ib = blockIdx.y, strm = blockIdx.z;
    int i = ib >> 1;
    int t = threadIdx.x;
    int l0 = lt * 64;
    size_t base = (size_t)ib * DI * LLEN;

    const f16 *inb; const float *cw, *cb;
    if (strm == 0)      { inb = mk_pre;   cw = conv_m_w + i * DI * 3; cb = conv_m_b + i * DI; }
    else if (strm == 1) { inb = info_pre; cw = conv_i_w + i * DI * 3; cb = conv_i_b + i * DI; }
    else                { inb = xc_pre;   cw = conv_x_w + i * DI * 3; cb = conv_x_b + i * DI; }

    // ---- conv: thread owns 4 channels x 8 l's ----
    {
        int d4 = t & 31, lq = t >> 5;
        int d = d4 * 4;
        float cw0[4], cw1[4], cw2[4], cbb[4];
        #pragma unroll
        for (int j = 0; j < 4; ++j) {
            cw0[j] = cw[(d + j) * 3 + 0];
            cw1[j] = cw[(d + j) * 3 + 1];
            cw2[j] = cw[(d + j) * 3 + 2];
            cbb[j] = cb[d + j];
        }
        int gl0 = l0 + lq * 8;
        float4 x0 = make_float4(0.f, 0.f, 0.f, 0.f), x1 = x0;
        if (gl0 >= 2) x0 = to_f4(*(const f16x4*)&inb[base + (size_t)(gl0 - 2) * DI + d]);
        if (gl0 >= 1) x1 = to_f4(*(const f16x4*)&inb[base + (size_t)(gl0 - 1) * DI + d]);
        #pragma unroll
        for (int li = 0; li < 8; ++li) {
            int l = lq * 8 + li;
            float4 x2 = to_f4(*(const f16x4*)&inb[base + (size_t)(gl0 + li) * DI + d]);
            float4 v;
            v.x = siluf(cw0[0] * x0.x + cw1[0] * x1.x + cw2[0] * x2.x + cbb[0]);
            v.y = siluf(cw0[1] * x0.y + cw1[1] * x1.y + cw2[1] * x2.y + cbb[1]);
            v.z = siluf(cw0[2] * x0.z + cw1[2] * x1.z + cw2[2] * x2.z + cbb[2]);
            v.w = siluf(cw0[3] * x0.w + cw1[3] * x1.w + cw2[3] * x2.w + cbb[3]);
            f16x4 hv = to_h4(v.x, v.y, v.z, v.w);
            *(f16x4*)&ot[swz16(l, d)] = hv;
            if (strm == 2) *(f16x4*)&u[base + (size_t)(gl0 + li) * DI + d] = hv;
            x0 = x1; x1 = x2;
        }
    }
    __syncthreads();

    if (strm == 0) {
        {
            int l = t & 63, r = t >> 6;
            const float* dw = delta_w + i * RR * DI + r * DI;
            float acc = 0.f;
            #pragma unroll
            for (int db = 0; db < 16; ++db) {
                f16x8 v = *(const f16x8*)&ot[swz16(l, db * 8)];
                int d0 = db * 8;
                #pragma unroll
                for (int j = 0; j < 8; ++j) acc += dw[d0 + j] * (float)v[j];
            }
            rvec[r * 64 + l] = acc;
        }
        __syncthreads();
        {
            int d = t & 127, lh = t >> 7;
            const float* dtw = dt_w + i * DI * RR + d * RR;
            float w0 = dtw[0], w1 = dtw[1], w2 = dtw[2], w3 = dtw[3];
            float bb = dt_b[i * DI + d];
            #pragma unroll 4
            for (int li = 0; li < 32; ++li) {
                int l = lh * 32 + li;
                float v = bb + w0 * rvec[l] + w1 * rvec[64 + l] + w2 * rvec[128 + l] + w3 * rvec[192 + l];
                float sp = (v > 20.f) ? v : log1pf(__expf(v));
                delta[base + (size_t)(l0 + l) * DI + d] = (f16)sp;
            }
        }
    } else {
        int l = t & 63, ng = t >> 6;
        const float* wv = ((strm == 1) ? B_w : C_w) + i * NN * DI + ng * 4 * DI;
        float a0 = 0.f, a1 = 0.f, a2 = 0.f, a3 = 0.f;
        #pragma unroll
        for (int db = 0; db < 16; ++db) {
            f16x8 v = *(const f16x8*)&ot[swz16(l, db * 8)];
            int d0 = db * 8;
            #pragma unroll
            for (int j = 0; j < 8; ++j) {
                float x = (float)v[j];
                a0 += wv[d0 + j] * x;
                a1 += wv[DI + d0 + j] * x;
                a2 += wv[2 * DI + d0 + j] * x;
                a3 += wv[3 * DI + d0 + j] * x;
            }
        }
        f16* dst = (strm == 1) ? Bm : Cm;
        *(f16x4*)&dst[((size_t)ib * LLEN + l0 + l) * NN + ng * 4] = to_h4(a0, a1, a2, a3);
    }
}

// ---------------------------------------------------------------------------
// Scan step macro shared by coop and fallback kernels (identical math).
// ---------------------------------------------------------------------------
#define SCAN_STEP_NOACC(dl, du, b0, b1, b2, b3)                                  \
    h[0] = __expf((dl) * A[0]) * h[0] + (du) * b0.x;                             \
    h[1] = __expf((dl) * A[1]) * h[1] + (du) * b0.y;                             \
    h[2] = __expf((dl) * A[2]) * h[2] + (du) * b0.z;                             \
    h[3] = __expf((dl) * A[3]) * h[3] + (du) * b0.w;                             \
    h[4] = __expf((dl) * A[4]) * h[4] + (du) * b1.x;                             \
    h[5] = __expf((dl) * A[5]) * h[5] + (du) * b1.y;                             \
    h[6] = __expf((dl) * A[6]) * h[6] + (du) * b1.z;                             \
    h[7] = __expf((dl) * A[7]) * h[7] + (du) * b1.w;                             \
    h[8] = __expf((dl) * A[8]) * h[8] + (du) * b2.x;                             \
    h[9] = __expf((dl) * A[9]) * h[9] + (du) * b2.y;                             \
    h[10] = __expf((dl) * A[10]) * h[10] + (du) * b2.z;                          \
    h[11] = __expf((dl) * A[11]) * h[11] + (du) * b2.w;                          \
    h[12] = __expf((dl) * A[12]) * h[12] + (du) * b3.x;                          \
    h[13] = __expf((dl) * A[13]) * h[13] + (du) * b3.y;                          \
    h[14] = __expf((dl) * A[14]) * h[14] + (du) * b3.z;                          \
    h[15] = __expf((dl) * A[15]) * h[15] + (du) * b3.w;

// ---------------------------------------------------------------------------
// K46 (cooperative): fused scan = pass1 -> grid.sync -> prefix -> grid.sync
// -> pass2. grid (256, 6) x 128 threads; thread owns (ib, d). Low-VGPR:
// pass 2 re-reads delta/u (no register caching).
// ---------------------------------------------------------------------------
__global__ __launch_bounds__(128) void k46_scan(
    const f16* __restrict__ u, const f16* __restrict__ delta,
    const f16* __restrict__ Bm, const f16* __restrict__ Cm,
    const float* __restrict__ A_log,
    f16* __restrict__ aprod, f16* __restrict__ hend,
    f16* __restrict__ hin, f16* __restrict__ y)
{
    __shared__ __align__(16) float sB[LC * 16];
    __shared__ __align__(16) float sC[LC * 16];
    cg::grid_group grid = cg::this_grid();

    int g = blockIdx.x, ib = blockIdx.y, i = ib >> 1;
    int d = threadIdx.x;
    {
        const f16x4* bsrc = (const f16x4*)(Bm + ((size_t)ib * LLEN + (size_t)g * LC) * NN);
        const f16x4* csrc = (const f16x4*)(Cm + ((size_t)ib * LLEN + (size_t)g * LC) * NN);
        if (d < 64) ((float4*)sB)[d] = to_f4(bsrc[d]);
        else ((float4*)sC)[d - 64] = to_f4(csrc[d - 64]);
    }
    float A[16], h[16];
    {
        const float4* al = (const float4*)(A_log + ((size_t)i * DI + d) * NN);
        #pragma unroll
        for (int q = 0; q < 4; ++q) {
            float4 v = al[q];
            A[4 * q] = -__expf(v.x); A[4 * q + 1] = -__expf(v.y);
            A[4 * q + 2] = -__expf(v.z); A[4 * q + 3] = -__expf(v.w);
        }
    }
    #pragma unroll
    for (int n = 0; n < 16; ++n) h[n] = 0.f;
    float sdl = 0.f;
    __syncthreads();

    size_t base = ((size_t)ib * LLEN + (size_t)g * LC) * DI + d;
    // ---- pass 1: per-chunk scan with h_in = 0 ----
    #pragma unroll 4
    for (int li = 0; li < LC; ++li) {
        float dl = (float)delta[base + li * DI];
        float du = dl * (float)u[base + li * DI];
        sdl += dl;
        const float4* bl = (const float4*)(sB + li * 16);
        float4 b0 = bl[0], b1 = bl[1], b2 = bl[2], b3 = bl[3];
        SCAN_STEP_NOACC(dl, du, b0, b1, b2, b3)
    }
    size_t seq = ((size_t)ib * DI + d) * NN;
    {
        f16x8* ap = (f16x8*)(aprod + (size_t)g * NSEQ + seq);
        f16x8* he = (f16x8*)(hend + (size_t)g * NSEQ + seq);
        #pragma unroll
        for (int q = 0; q < 2; ++q) {
            f16x8 av, hv;
            #pragma unroll
            for (int j = 0; j < 8; ++j) {
                av[j] = (f16)__expf(A[8 * q + j] * sdl);
                hv[j] = (f16)h[8 * q + j];
            }
            ap[q] = av; he[q] = hv;
        }
    }

    grid.sync();

    // ---- prefix: first 96 blocks (12288 threads) ----
    {
        int flat = blockIdx.y * (int)gridDim.x + blockIdx.x;
        int s = flat * 128 + (int)threadIdx.x;
        if (s < NSEQ) {
            float hh = 0.f;
            #pragma unroll 8
            for (int gg = 0; gg < GG; ++gg) {
                hin[(size_t)gg * NSEQ + s] = (f16)hh;
                hh = (float)aprod[(size_t)gg * NSEQ + s] * hh + (float)hend[(size_t)gg * NSEQ + s];
            }
        }
    }

    grid.sync();

    // ---- pass 2: replay with h_in from hin; re-read delta/u ----
    {
        const f16x8* hp = (const f16x8*)(hin + (size_t)g * NSEQ + seq);
        #pragma unroll
        for (int q = 0; q < 2; ++q) {
            f16x8 v = hp[q];
            #pragma unroll
            for (int j = 0; j < 8; ++j) h[8 * q + j] = (float)v[j];
        }
    }
    #pragma unroll 4
    for (int li = 0; li < LC; ++li) {
        float dl = (float)delta[base + li * DI];
        float du = dl * (float)u[base + li * DI];
        const float4* bl = (const float4*)(sB + li * 16);
        const float4* cl = (const float4*)(sC + li * 16);
        float4 b0 = bl[0], b1 = bl[1], b2 = bl[2], b3 = bl[3];
        float4 c0 = cl[0], c1 = cl[1], c2 = cl[2], c3 = cl[3];
        SCAN_STEP_NOACC(dl, du, b0, b1, b2, b3)
        float acc = h[0] * c0.x + h[1] * c0.y + h[2] * c0.z + h[3] * c0.w
                  + h[4] * c1.x + h[5] * c1.y + h[6] * c1.z + h[7] * c1.w
                  + h[8] * c2.x + h[9] * c2.y + h[10] * c2.z + h[11] * c2.w
                  + h[12] * c3.x + h[13] * c3.y + h[14] * c3.z + h[15] * c3.w;
        y[base + li * DI] = (f16)acc;
    }
}

// ---------------------------------------------------------------------------
// K4 (fallback): scan pass 1. grid (256,6)x128.  [round-9 verbatim]
// ---------------------------------------------------------------------------
__global__ __launch_bounds__(128) void k4_scan1(
    const f16* __restrict__ u, const f16* __restrict__ delta,
    const f16* __restrict__ Bm, const float* __restrict__ A_log,
    f16* __restrict__ aprod, f16* __restrict__ hend)
{
    __shared__ __align__(16) float sB[LC * 16];
    int g = blockIdx.x, ib = blockIdx.y, i = ib >> 1;
    int d = threadIdx.x;
    if (d < 64) {
        f16x4 v = ((const f16x4*)(Bm + ((size_t)ib * LLEN + (size_t)g * LC) * NN))[d];
        ((float4*)sB)[d] = to_f4(v);
    }
    float A[16], h[16];
    {
        const float4* al = (const float4*)(A_log + ((size_t)i * DI + d) * NN);
        #pragma unroll
        for (int q = 0; q < 4; ++q) {
            float4 v = al[q];
            A[4 * q] = -__expf(v.x); A[4 * q + 1] = -__expf(v.y);
            A[4 * q + 2] = -__expf(v.z); A[4 * q + 3] = -__expf(v.w);
        }
    }
    #pragma unroll
    for (int n = 0; n < 16; ++n) h[n] = 0.f;
    float sdl = 0.f;
    __syncthreads();
    size_t base = ((size_t)ib * LLEN + (size_t)g * LC) * DI + d;
    #pragma unroll 4
    for (int li = 0; li < LC; ++li) {
        float dl = (float)delta[base + li * DI];
        float du = dl * (float)u[base + li * DI];
        sdl += dl;
        const float4* bl = (const float4*)(sB + li * 16);
        float4 b0 = bl[0], b1 = bl[1], b2 = bl[2], b3 = bl[3];
        SCAN_STEP_NOACC(dl, du, b0, b1, b2, b3)
    }
    size_t seq = ((size_t)ib * DI + d) * NN;
    f16x8* ap = (f16x8*)(aprod + (size_t)g * NSEQ + seq);
    f16x8* he = (f16x8*)(hend + (size_t)g * NSEQ + seq);
    #pragma unroll
    for (int q = 0; q < 2; ++q) {
        f16x8 av, hv;
        #pragma unroll
        for (int j = 0; j < 8; ++j) {
            av[j] = (f16)__expf(A[8 * q + j] * sdl);
            hv[j] = (f16)h[8 * q + j];
        }
        ap[q] = av; he[q] = hv;
    }
}

// ---------------------------------------------------------------------------
// K5 (fallback): chunk-prefix over G=256.  [round-9 verbatim]
// ---------------------------------------------------------------------------
__global__ __launch_bounds__(256) void k5_prefix(
    const f16* __restrict__ aprod, const f16* __restrict__ hend,
    f16* __restrict__ hin)
{
    int s = blockIdx.x * 256 + threadIdx.x;
    float h = 0.f;
    #pragma unroll 8
    for (int g = 0; g < GG; ++g) {
        hin[(size_t)g * NSEQ + s] = (f16)h;
        h = (float)aprod[(size_t)g * NSEQ + s] * h + (float)hend[(size_t)g * NSEQ + s];
    }
}

// ---------------------------------------------------------------------------
// K6 (fallback): scan pass 2.  [round-9 verbatim math]
// ---------------------------------------------------------------------------
__global__ __launch_bounds__(128) void k6_scan2(
    const f16* __restrict__ u, const f16* __restrict__ delta,
    const f16* __restrict__ Bm, const f16* __restrict__ Cm,
    const float* __restrict__ A_log, const f16* __restrict__ hin,
    f16* __restrict__ y)
{
    __shared__ __align__(16) float sB[LC * 16];
    __shared__ __align__(16) float sC[LC * 16];
    int g = blockIdx.x, ib = blockIdx.y, i = ib >> 1;
    int d = threadIdx.x;
    {
        const f16x4* bsrc = (const f16x4*)(Bm + ((size_t)ib * LLEN + (size_t)g * LC) * NN);
        const f16x4* csrc = (const f16x4*)(Cm + ((size_t)ib * LLEN + (size_t)g * LC) * NN);
        if (d < 64) ((float4*)sB)[d] = to_f4(bsrc[d]);
        else ((float4*)sC)[d - 64] = to_f4(csrc[d - 64]);
    }
    float A[16], h[16];
    {
        const float4* al = (const float4*)(A_log + ((size_t)i * DI + d) * NN);
        #pragma unroll
        for (int q = 0; q < 4; ++q) {
            float4 v = al[q];
            A[4 * q] = -__expf(v.x); A[4 * q + 1] = -__expf(v.y);
            A[4 * q + 2] = -__expf(v.z); A[4 * q + 3] = -__expf(v.w);
        }
    }
    {
        size_t seq = ((size_t)ib * DI + d) * NN;
        const f16x8* hp = (const f16x8*)(hin + (size_t)g * NSEQ + seq);
        #pragma unroll
        for (int q = 0; q < 2; ++q) {
            f16x8 v = hp[q];
            #pragma unroll
            for (int j = 0; j < 8; ++j) h[8 * q + j] = (float)v[j];
        }
    }
    __syncthreads();
    size_t base = ((size_t)ib * LLEN + (size_t)g * LC) * DI + d;
    #pragma unroll 4
    for (int li = 0; li < LC; ++li) {
        float dl = (float)delta[base + li * DI];
        float du = dl * (float)u[base + li * DI];
        const float4* bl = (const float4*)(sB + li * 16);
        const float4* cl = (const float4*)(sC + li * 16);
        float4 b0 = bl[0], b1 = bl[1], b2 = bl[2], b3 = bl[3];
        float4 c0 = cl[0], c1 = cl[1], c2 = cl[2], c3 = cl[3];
        SCAN_STEP_NOACC(dl, du, b0, b1, b2, b3)
        float acc = h[0] * c0.x + h[1] * c0.y + h[2] * c0.z + h[3] * c0.w
                  + h[4] * c1.x + h[5] * c1.y + h[6] * c1.z + h[7] * c1.w
                  + h[8] * c2.x + h[9] * c2.y + h[10] * c2.z + h[11] * c2.w
                  + h[12] * c3.x + h[13] * c3.y + h[14] * c3.z + h[15] * c3.w;
        y[base + li * DI] = (f16)acc;
    }
}

// ---------------------------------------------------------------------------
// K7 (MFMA): y*silu(x_act), out-proj DI->C summed over branches, + residuals.
// grid (64 ltile, 2 b), 256 threads = 4 waves.  [round-9 verbatim]
// ---------------------------------------------------------------------------
__global__ __launch_bounds__(256) void k7_out(
    const f16* __restrict__ y, const f16* __restrict__ xact,
    const float* __restrict__ out_w,
    const float* __restrict__ fx, const float* __restrict__ fy, const float* __restrict__ fz,
    float* __restrict__ out)
{
    __shared__ short sG[64 * 128]; // [l][d] bf16, 16B-block XOR swizzle
    int lt = blockIdx.x, b = blockIdx.y;
    int l0 = lt * 64;
    int t = threadIdx.x;
    int w = t >> 6, lane = t & 63, lo = lane & 15, hi = lane >> 4;

    f32x4 acc[4];
    #pragma unroll
    for (int nt = 0; nt < 4; ++nt) acc[nt] = (f32x4){0.f, 0.f, 0.f, 0.f};

    for (int i = 0; i < 3; ++i) {
        size_t base = ((size_t)(i * 2 + b)) * DI * LLEN;
        __syncthreads();
        #pragma unroll
        for (int p = 0; p < 8; ++p) {
            int idx = t + 256 * p; // 2048 = 64 l x 32 d4
            int d4 = idx & 31, l = idx >> 5;
            int d = d4 * 4;
            float4 yv = to_f4(*(const f16x4*)&y[base + (size_t)(l0 + l) * DI + d]);
            float4 xa = to_f4(*(const f16x4*)&xact[base + (size_t)(l0 + l) * DI + d]);
            float g0 = yv.x * siluf(xa.x), g1 = yv.y * siluf(xa.y);
            float g2 = yv.z * siluf(xa.z), g3 = yv.w * siluf(xa.w);
            int blk = d4 >> 1;
            int blks = (blk & 8) | ((blk ^ (l & 7)) & 7);
            unsigned* p32 = (unsigned*)&sG[l * 128 + blks * 8 + 4 * (d4 & 1)];
            p32[0] = pack_bf16(g0, g1);
            p32[1] = pack_bf16(g2, g3);
        }
        __syncthreads();

        const float* ow = out_w + (size_t)i * CC * DI;
        bf16x8 a[4];
        #pragma unroll
        for (int ks = 0; ks < 4; ++ks) {
            const float* ap = ow + (size_t)(16 * w + lo) * 128 + ks * 32 + hi * 8;
            a[ks] = pack8(*(const float4*)ap, *(const float4*)(ap + 4));
        }
        #pragma unroll
        for (int nt = 0; nt < 4; ++nt) {
            int l = 16 * nt + lo;
            #pragma unroll
            for (int ks = 0; ks < 4; ++ks) {
                int db = ks * 4 + hi;
                int blks = (db & 8) | ((db ^ (l & 7)) & 7);
                bf16x8 bv = *(const bf16x8*)&sG[l * 128 + blks * 8];
                acc[nt] = __builtin_amdgcn_mfma_f32_16x16x32_bf16(a[ks], bv, acc[nt], 0, 0, 0);
            }
        }
    }

    // epilogue: + residuals, write out[b][c][l]
    #pragma unroll
    for (int nt = 0; nt < 4; ++nt) {
        int l = l0 + 16 * nt + lo;
        int cbase = 16 * w + 4 * hi;
        #pragma unroll
        for (int rr = 0; rr < 4; ++rr) {
            int c = cbase + rr;
            size_t idx = ((size_t)b * CC + c) * LLEN + l;
            out[idx] = acc[nt][rr] + fx[idx] + fy[idx] + fz[idx];
        }
    }
}

} // namespace

extern "C" void kernel_launch(void* const* d_in, const int* in_sizes, int n_in,
                              void* d_out, int out_size, void* d_ws, size_t ws_size,
                              hipStream_t stream)
{
    (void)in_sizes; (void)n_in; (void)out_size; (void)ws_size;
    const float* up       = (const float*)d_in[0];
    const float* mask_    = (const float*)d_in[1];
    const float* fx       = (const float*)d_in[2];
    const float* fy       = (const float*)d_in[3];
    const float* fz       = (const float*)d_in[4];
    const float* pe_x_w   = (const float*)d_in[5];
    const float* pe_x_b   = (const float*)d_in[6];
    const float* rms_x_w  = (const float*)d_in[7];
    const float* conv_x_w = (const float*)d_in[8];
    const float* conv_x_b = (const float*)d_in[9];
    const float* pe_i_w   = (const float*)d_in[10];
    const float* pe_i_b   = (const float*)d_in[11];
    const float* rms_i_w  = (const float*)d_in[12];
    const float* conv_i_w = (const float*)d_in[13];
    const float* conv_i_b = (const float*)d_in[14];
    const float* pe_m_w   = (const float*)d_in[15];
    const float* pe_m_b   = (const float*)d_in[16];
    const float* rms_m_w  = (const float*)d_in[17];
    const float* conv_m_w = (const float*)d_in[18];
    const float* conv_m_b = (const float*)d_in[19];
    const float* in_x_w   = (const float*)d_in[20];
    const float* in_i_w   = (const float*)d_in[21];
    const float* in_m_w   = (const float*)d_in[22];
    const float* delta_w  = (const float*)d_in[23];
    const float* dt_w     = (const float*)d_in[24];
    const float* dt_b     = (const float*)d_in[25];
    const float* B_w      = (const float*)d_in[26];
    const float* C_w      = (const float*)d_in[27];
    const float* A_log    = (const float*)d_in[28];
    const float* out_w    = (const float*)d_in[29];
    float* out = (float*)d_out;

    // f16 workspace layout (slot = SBUF f16 elems = 6.3 MB) [round-9 verbatim]:
    f16* ws = (f16*)d_ws;
    const size_t S = SBUF;
    f16* xc_pre   = ws;          // dead after K3 -> hin
    f16* x_act    = ws + S;      // live until K7
    f16* info_pre = ws + 2 * S;  // dead after K3 -> aprod -> y
    f16* mk_pre   = ws + 3 * S;  // dead after K3 -> hend
    f16* ubuf     = ws + 4 * S;
    f16* dbuf     = ws + 5 * S;
    f16* BmB      = ws + 6 * S;
    f16* CmB      = BmB + (size_t)NB * BB * NN * LLEN;
    f16* aprod = info_pre;  // GG*NSEQ = 3145728 = S elems
    f16* hendb = mk_pre;
    f16* hinb  = xc_pre;
    f16* ybuf  = info_pre;  // overwrites aprod (dead after prefix; ordered by grid sync / k5)

    hipLaunchKernelGGL(k1_embed, dim3(64, 9, 2), dim3(256), 0, stream,
        up, mask_, fx, fy, fz,
        pe_x_w, pe_x_b, rms_x_w, pe_i_w, pe_i_b, rms_i_w, pe_m_w, pe_m_b, rms_m_w,
        in_x_w, in_i_w, in_m_w, xc_pre, x_act, info_pre, mk_pre);

    hipLaunchKernelGGL(k3_conv, dim3(64, 6, 3), dim3(256), 0, stream,
        xc_pre, info_pre, mk_pre,
        conv_x_w, conv_x_b, conv_i_w, conv_i_b, conv_m_w, conv_m_b,
        delta_w, dt_w, dt_b, B_w, C_w, ubuf, dbuf, BmB, CmB);

    // Cooperative fused scan; math-identical fallback to 3-kernel path on any
    // launch error (e.g. cooperative capacity / capture restrictions).
    hipError_t ce;
    {
        const f16* a_u = ubuf; const f16* a_d = dbuf;
        const f16* a_B = BmB;  const f16* a_C = CmB;
        const float* a_A = A_log;
        f16* a_ap = aprod; f16* a_he = hendb; f16* a_hi = hinb; f16* a_y = ybuf;
        void* args[] = { &a_u, &a_d, &a_B, &a_C, &a_A, &a_ap, &a_he, &a_hi, &a_y };
        ce = hipLaunchCooperativeKernel((const void*)k46_scan, dim3(GG, 6), dim3(128),
                                        args, 0, stream);
    }
    if (ce != hipSuccess) {
        hipLaunchKernelGGL(k4_scan1, dim3(GG, 6), dim3(128), 0, stream,
            ubuf, dbuf, BmB, A_log, aprod, hendb);
        hipLaunchKernelGGL(k5_prefix, dim3(NSEQ / 256), dim3(256), 0, stream,
            aprod, hendb, hinb);
        hipLaunchKernelGGL(k6_scan2, dim3(GG, 6), dim3(128), 0, stream,
            ubuf, dbuf, BmB, CmB, A_log, hinb, ybuf);
    }

    hipLaunchKernelGGL(k7_out, dim3(64, 2), dim3(256), 0, stream,
        ybuf, x_act, out_w, fx, fy, fz, out);
}

// Round 12
// 116.409 us; speedup vs baseline: 3.5372x; 3.5372x over previous
//
#include <hip/hip_runtime.h>
#include <math.h>

namespace {

constexpr int NB = 3;      // branches
constexpr int BB = 2;      // batch
constexpr int CC = 64;     // channels
constexpr int LLEN = 4096; // H*W
constexpr int DI = 128;    // inner dim
constexpr int NN = 16;     // state dim
constexpr int RR = 4;      // rank
constexpr int GG = 256;    // scan chunks
constexpr int LC = 16;     // chunk length
constexpr int NSEQ = NB * BB * DI * NN; // 12288 scan sequences
constexpr size_t SBUF = (size_t)NB * BB * DI * LLEN; // 3145728 elems per big slot

typedef _Float16 f16;
typedef __attribute__((ext_vector_type(4))) float f32x4;
typedef __attribute__((ext_vector_type(8))) short bf16x8;
typedef __attribute__((ext_vector_type(4))) _Float16 f16x4;
typedef __attribute__((ext_vector_type(8))) _Float16 f16x8;

__device__ __forceinline__ float siluf(float v) { return v / (1.f + __expf(-v)); }

__device__ __forceinline__ short cvt_bf16(float f) {
    union { float f; unsigned u; } v; v.f = f;
    unsigned r = v.u + 0x7fffu + ((v.u >> 16) & 1u);
    return (short)(r >> 16);
}
__device__ __forceinline__ unsigned pack_bf16(float lo, float hi) {
    return ((unsigned)(unsigned short)cvt_bf16(hi) << 16) | (unsigned short)cvt_bf16(lo);
}
__device__ __forceinline__ bf16x8 pack8(float4 a, float4 b) {
    bf16x8 r;
    r[0] = cvt_bf16(a.x); r[1] = cvt_bf16(a.y); r[2] = cvt_bf16(a.z); r[3] = cvt_bf16(a.w);
    r[4] = cvt_bf16(b.x); r[5] = cvt_bf16(b.y); r[6] = cvt_bf16(b.z); r[7] = cvt_bf16(b.w);
    return r;
}
__device__ __forceinline__ f16x4 to_h4(float a, float b, float c, float d) {
    f16x4 r; r[0] = (f16)a; r[1] = (f16)b; r[2] = (f16)c; r[3] = (f16)d; return r;
}
__device__ __forceinline__ float4 to_f4(f16x4 v) {
    return make_float4((float)v[0], (float)v[1], (float)v[2], (float)v[3]);
}
// f16 LDS tile [64 l][128 d]: 16B blocks (8 f16), XOR-swizzled slot (round-7 proven)
__device__ __forceinline__ int swz16(int l, int d) {
    int b = d >> 3;
    int bs = (b & 8) | ((b ^ l) & 7);
    return l * 128 + bs * 8 + (d & 7);
}

// ---------------------------------------------------------------------------
// K1 (MFMA): embed1x1 + bias + rms + projection. Outputs l-major fp16 [ib][l][d].
// grid (64 ltile, 9 jobs, 2 b), 256 threads = 4 waves.  [round-9 verbatim]
// ---------------------------------------------------------------------------
__global__ __launch_bounds__(256) void k1_embed(
    const float* __restrict__ up, const float* __restrict__ mask_,
    const float* __restrict__ fx, const float* __restrict__ fy, const float* __restrict__ fz,
    const float* __restrict__ pe_x_w, const float* __restrict__ pe_x_b, const float* __restrict__ rms_x_w,
    const float* __restrict__ pe_i_w, const float* __restrict__ pe_i_b, const float* __restrict__ rms_i_w,
    const float* __restrict__ pe_m_w, const float* __restrict__ pe_m_b, const float* __restrict__ rms_m_w,
    const float* __restrict__ in_x_w, const float* __restrict__ in_i_w, const float* __restrict__ in_m_w,
    f16* __restrict__ xc_pre, f16* __restrict__ x_act,
    f16* __restrict__ info_pre, f16* __restrict__ mk_pre)
{
    __shared__ short sE[64 * 64];   // En bf16, [l][o] with 16B-block XOR swizzle
    __shared__ float red[4][64];
    __shared__ float sscl[64];

    int lt = blockIdx.x, job = blockIdx.y, b = blockIdx.z;
    int i = job / 3, r = job % 3;
    const float *src, *pw, *pb, *rw, *iw;
    if (r == 0) {
        src = (i == 0 ? fx : (i == 1 ? fy : fz));
        pw = pe_x_w + i * 4096; pb = pe_x_b + i * 64; rw = rms_x_w + i * 64;
        iw = in_x_w + (size_t)i * 256 * 64;
    } else if (r == 1) {
        src = up;
        pw = pe_i_w + i * 4096; pb = pe_i_b + i * 64; rw = rms_i_w + i * 64;
        iw = in_i_w + (size_t)i * 128 * 64;
    } else {
        src = mask_;
        pw = pe_m_w + i * 4096; pb = pe_m_b + i * 64; rw = rms_m_w + i * 64;
        iw = in_m_w + (size_t)i * 128 * 64;
    }
    int t = threadIdx.x;
    int w = t >> 6, lane = t & 63, lo = lane & 15, hi = lane >> 4;
    int l0 = lt * 64;
    const float* Xg = src + (size_t)b * 64 * LLEN;

    // ---- MFMA #1: E = W1 @ X ----
    f32x4 acc1[4];
    #pragma unroll
    for (int nt = 0; nt < 4; ++nt) acc1[nt] = (f32x4){0.f, 0.f, 0.f, 0.f};

    #pragma unroll
    for (int ks = 0; ks < 2; ++ks) {
        const float* ap = pw + (16 * w + lo) * 64 + ks * 32 + hi * 8;
        bf16x8 a1 = pack8(*(const float4*)ap, *(const float4*)(ap + 4));
        #pragma unroll
        for (int nt = 0; nt < 4; ++nt) {
            const float* xc = Xg + (size_t)(ks * 32 + hi * 8) * LLEN + l0 + nt * 16 + lo;
            bf16x8 b1;
            #pragma unroll
            for (int j = 0; j < 8; ++j) b1[j] = cvt_bf16(xc[(size_t)j * LLEN]);
            acc1[nt] = __builtin_amdgcn_mfma_f32_16x16x32_bf16(a1, b1, acc1[nt], 0, 0, 0);
        }
    }

    // ---- bias + rms reduction ----
    float4 pbv = *(const float4*)&pb[16 * w + 4 * hi];
    float e_[4][4];
    #pragma unroll
    for (int nt = 0; nt < 4; ++nt) {
        e_[nt][0] = acc1[nt][0] + pbv.x;
        e_[nt][1] = acc1[nt][1] + pbv.y;
        e_[nt][2] = acc1[nt][2] + pbv.z;
        e_[nt][3] = acc1[nt][3] + pbv.w;
        float s = e_[nt][0] * e_[nt][0] + e_[nt][1] * e_[nt][1]
                + e_[nt][2] * e_[nt][2] + e_[nt][3] * e_[nt][3];
        s += __shfl_xor(s, 16);
        s += __shfl_xor(s, 32);
        if (lane < 16) red[w][nt * 16 + lo] = s;
    }
    __syncthreads();
    if (t < 64) {
        float s = red[0][t] + red[1][t] + red[2][t] + red[3][t];
        sscl[t] = rsqrtf(s * (1.f / 64.f) + 1e-5f);
    }
    __syncthreads();

    // ---- En -> bf16 swizzled LDS [l][o] ----
    {
        int ob = 2 * w + (hi >> 1);
        #pragma unroll
        for (int nt = 0; nt < 4; ++nt) {
            float sc = sscl[16 * nt + lo];
            unsigned p0 = pack_bf16(e_[nt][0] * sc, e_[nt][1] * sc);
            unsigned p1 = pack_bf16(e_[nt][2] * sc, e_[nt][3] * sc);
            unsigned* p = (unsigned*)&sE[(16 * nt + lo) * 64 + (ob ^ (lo & 7)) * 8 + 4 * (hi & 1)];
            p[0] = p0; p[1] = p1;
        }
    }
    __syncthreads();

    // ---- MFMA #2 ----
    bf16x8 b2[4][2];
    #pragma unroll
    for (int nt = 0; nt < 4; ++nt)
        #pragma unroll
        for (int ks = 0; ks < 2; ++ks) {
            int db = ks * 4 + hi;
            b2[nt][ks] = *(const bf16x8*)&sE[(16 * nt + lo) * 64 + (db ^ (lo & 7)) * 8];
        }

    size_t obase = ((size_t)(i * 2 + b)) * DI * LLEN;
    int MT = (r == 0) ? 4 : 2; // M-tiles per wave
    for (int mm = 0; mm < MT; ++mm) {
        int m = MT * w + mm;
        bf16x8 a2[2];
        #pragma unroll
        for (int ks = 0; ks < 2; ++ks) {
            const float* wp = iw + (size_t)(16 * m + lo) * 64 + ks * 32 + hi * 8;
            float4 w0 = *(const float4*)wp;
            float4 w1 = *(const float4*)(wp + 4);
            float4 r0 = *(const float4*)&rw[ks * 32 + hi * 8];
            float4 r1 = *(const float4*)&rw[ks * 32 + hi * 8 + 4];
            w0.x *= r0.x; w0.y *= r0.y; w0.z *= r0.z; w0.w *= r0.w;
            w1.x *= r1.x; w1.y *= r1.y; w1.z *= r1.z; w1.w *= r1.w;
            a2[ks] = pack8(w0, w1);
        }
        f32x4 acc2[4];
        #pragma unroll
        for (int nt = 0; nt < 4; ++nt) acc2[nt] = (f32x4){0.f, 0.f, 0.f, 0.f};
        #pragma unroll
        for (int ks = 0; ks < 2; ++ks)
            #pragma unroll
            for (int nt = 0; nt < 4; ++nt)
                acc2[nt] = __builtin_amdgcn_mfma_f32_16x16x32_bf16(a2[ks], b2[nt][ks], acc2[nt], 0, 0, 0);

        int d0 = 16 * m + 4 * hi;
        f16* dst; int dd = d0;
        if (r == 0) { if (d0 < 128) dst = xc_pre; else { dst = x_act; dd = d0 - 128; } }
        else if (r == 1) dst = info_pre;
        else dst = mk_pre;
        #pragma unroll
        for (int nt = 0; nt < 4; ++nt) {
            int l = l0 + 16 * nt + lo;
            *(f16x4*)&dst[obase + (size_t)l * DI + dd] =
                to_h4(acc2[nt][0], acc2[nt][1], acc2[nt][2], acc2[nt][3]);
        }
    }
}

// ---------------------------------------------------------------------------
// K3: causal dwconv(K=3)+SiLU + matvec, ONE stream per block.
// grid (64 ltile, 6 ib, 3 stream), 256 threads.  [round-9 verbatim]
// ---------------------------------------------------------------------------
__global__ __launch_bounds__(256) void k3_conv(
    const f16* __restrict__ xc_pre, const f16* __restrict__ info_pre, const f16* __restrict__ mk_pre,
    const float* __restrict__ conv_x_w, const float* __restrict__ conv_x_b,
    const float* __restrict__ conv_i_w, const float* __restrict__ conv_i_b,
    const float* __restrict__ conv_m_w, const float* __restrict__ conv_m_b,
    const float* __restrict__ delta_w, const float* __restrict__ dt_w, const float* __restrict__ dt_b,
    const float* __restrict__ B_w, const float* __restrict__ C_w,
    f16* __restrict__ u, f16* __restrict__ delta,
    f16* __restrict__ Bm, f16* __restrict__ Cm)
{
    __shared__ __align__(16) f16 ot[64 * 128]; // [l][d] swz16, 16 KB
    __shared__ float rvec[4 * 64];             // [r][l]

    int lt = blockIdx.x, ib = blockIdx.y, strm = blockIdx.z;
    int i = ib >> 1;
    int t = threadIdx.x;
    int l0 = lt * 64;
    size_t base = (size_t)ib * DI * LLEN;

    const f16 *inb; const float *cw, *cb;
    if (strm == 0)      { inb = mk_pre;   cw = conv_m_w + i * DI * 3; cb = conv_m_b + i * DI; }
    else if (strm == 1) { inb = info_pre; cw = conv_i_w + i * DI * 3; cb = conv_i_b + i * DI; }
    else                { inb = xc_pre;   cw = conv_x_w + i * DI * 3; cb = conv_x_b + i * DI; }

    // ---- conv: thread owns 4 channels x 8 l's ----
    {
        int d4 = t & 31, lq = t >> 5;
        int d = d4 * 4;
        float cw0[4], cw1[4], cw2[4], cbb[4];
        #pragma unroll
        for (int j = 0; j < 4; ++j) {
            cw0[j] = cw[(d + j) * 3 + 0];
            cw1[j] = cw[(d + j) * 3 + 1];
            cw2[j] = cw[(d + j) * 3 + 2];
            cbb[j] = cb[d + j];
        }
        int gl0 = l0 + lq * 8;
        float4 x0 = make_float4(0.f, 0.f, 0.f, 0.f), x1 = x0;
        if (gl0 >= 2) x0 = to_f4(*(const f16x4*)&inb[base + (size_t)(gl0 - 2) * DI + d]);
        if (gl0 >= 1) x1 = to_f4(*(const f16x4*)&inb[base + (size_t)(gl0 - 1) * DI + d]);
        #pragma unroll
        for (int li = 0; li < 8; ++li) {
            int l = lq * 8 + li;
            float4 x2 = to_f4(*(const f16x4*)&inb[base + (size_t)(gl0 + li) * DI + d]);
            float4 v;
            v.x = siluf(cw0[0] * x0.x + cw1[0] * x1.x + cw2[0] * x2.x + cbb[0]);
            v.y = siluf(cw0[1] * x0.y + cw1[1] * x1.y + cw2[1] * x2.y + cbb[1]);
            v.z = siluf(cw0[2] * x0.z + cw1[2] * x1.z + cw2[2] * x2.z + cbb[2]);
            v.w = siluf(cw0[3] * x0.w + cw1[3] * x1.w + cw2[3] * x2.w + cbb[3]);
            f16x4 hv = to_h4(v.x, v.y, v.z, v.w);
            *(f16x4*)&ot[swz16(l, d)] = hv;
            if (strm == 2) *(f16x4*)&u[base + (size_t)(gl0 + li) * DI + d] = hv;
            x0 = x1; x1 = x2;
        }
    }
    __syncthreads();

    if (strm == 0) {
        {
            int l = t & 63, r = t >> 6;
            const float* dw = delta_w + i * RR * DI + r * DI;
            float acc = 0.f;
            #pragma unroll
            for (int db = 0; db < 16; ++db) {
                f16x8 v = *(const f16x8*)&ot[swz16(l, db * 8)];
                int d0 = db * 8;
                #pragma unroll
                for (int j = 0; j < 8; ++j) acc += dw[d0 + j] * (float)v[j];
            }
            rvec[r * 64 + l] = acc;
        }
        __syncthreads();
        {
            int d = t & 127, lh = t >> 7;
            const float* dtw = dt_w + i * DI * RR + d * RR;
            float w0 = dtw[0], w1 = dtw[1], w2 = dtw[2], w3 = dtw[3];
            float bb = dt_b[i * DI + d];
            #pragma unroll 4
            for (int li = 0; li < 32; ++li) {
                int l = lh * 32 + li;
                float v = bb + w0 * rvec[l] + w1 * rvec[64 + l] + w2 * rvec[128 + l] + w3 * rvec[192 + l];
                float sp = (v > 20.f) ? v : log1pf(__expf(v));
                delta[base + (size_t)(l0 + l) * DI + d] = (f16)sp;
            }
        }
    } else {
        int l = t & 63, ng = t >> 6;
        const float* wv = ((strm == 1) ? B_w : C_w) + i * NN * DI + ng * 4 * DI;
        float a0 = 0.f, a1 = 0.f, a2 = 0.f, a3 = 0.f;
        #pragma unroll
        for (int db = 0; db < 16; ++db) {
            f16x8 v = *(const f16x8*)&ot[swz16(l, db * 8)];
            int d0 = db * 8;
            #pragma unroll
            for (int j = 0; j < 8; ++j) {
                float x = (float)v[j];
                a0 += wv[d0 + j] * x;
                a1 += wv[DI + d0 + j] * x;
                a2 += wv[2 * DI + d0 + j] * x;
                a3 += wv[3 * DI + d0 + j] * x;
            }
        }
        f16* dst = (strm == 1) ? Bm : Cm;
        *(f16x4*)&dst[((size_t)ib * LLEN + l0 + l) * NN + ng * 4] = to_h4(a0, a1, a2, a3);
    }
}

// ---------------------------------------------------------------------------
// K4: scan pass 1 — thread owns (ib,d), h[16]+A[16] in regs. grid (256,6)x128.
// [round-9 verbatim]
// ---------------------------------------------------------------------------
__global__ __launch_bounds__(128) void k4_scan1(
    const f16* __restrict__ u, const f16* __restrict__ delta,
    const f16* __restrict__ Bm, const float* __restrict__ A_log,
    f16* __restrict__ aprod, f16* __restrict__ hend)
{
    __shared__ __align__(16) float sB[LC * 16];
    int g = blockIdx.x, ib = blockIdx.y, i = ib >> 1;
    int d = threadIdx.x;
    if (d < 64) {
        f16x4 v = ((const f16x4*)(Bm + ((size_t)ib * LLEN + (size_t)g * LC) * NN))[d];
        ((float4*)sB)[d] = to_f4(v);
    }
    float A[16], h[16];
    {
        const float4* al = (const float4*)(A_log + ((size_t)i * DI + d) * NN);
        #pragma unroll
        for (int q = 0; q < 4; ++q) {
            float4 v = al[q];
            A[4 * q] = -__expf(v.x); A[4 * q + 1] = -__expf(v.y);
            A[4 * q + 2] = -__expf(v.z); A[4 * q + 3] = -__expf(v.w);
        }
    }
    #pragma unroll
    for (int n = 0; n < 16; ++n) h[n] = 0.f;
    float sdl = 0.f;
    __syncthreads();
    size_t base = ((size_t)ib * LLEN + (size_t)g * LC) * DI + d;
    #pragma unroll 4
    for (int li = 0; li < LC; ++li) {
        float dl = (float)delta[base + li * DI];
        float du = dl * (float)u[base + li * DI];
        sdl += dl;
        const float4* bl = (const float4*)(sB + li * 16);
        float4 b0 = bl[0], b1 = bl[1], b2 = bl[2], b3 = bl[3];
        h[0] = __expf(dl * A[0]) * h[0] + du * b0.x;  h[1] = __expf(dl * A[1]) * h[1] + du * b0.y;
        h[2] = __expf(dl * A[2]) * h[2] + du * b0.z;  h[3] = __expf(dl * A[3]) * h[3] + du * b0.w;
        h[4] = __expf(dl * A[4]) * h[4] + du * b1.x;  h[5] = __expf(dl * A[5]) * h[5] + du * b1.y;
        h[6] = __expf(dl * A[6]) * h[6] + du * b1.z;  h[7] = __expf(dl * A[7]) * h[7] + du * b1.w;
        h[8] = __expf(dl * A[8]) * h[8] + du * b2.x;  h[9] = __expf(dl * A[9]) * h[9] + du * b2.y;
        h[10] = __expf(dl * A[10]) * h[10] + du * b2.z; h[11] = __expf(dl * A[11]) * h[11] + du * b2.w;
        h[12] = __expf(dl * A[12]) * h[12] + du * b3.x; h[13] = __expf(dl * A[13]) * h[13] + du * b3.y;
        h[14] = __expf(dl * A[14]) * h[14] + du * b3.z; h[15] = __expf(dl * A[15]) * h[15] + du * b3.w;
    }
    size_t seq = ((size_t)ib * DI + d) * NN;
    f16x8* ap = (f16x8*)(aprod + (size_t)g * NSEQ + seq);
    f16x8* he = (f16x8*)(hend + (size_t)g * NSEQ + seq);
    #pragma unroll
    for (int q = 0; q < 2; ++q) {
        f16x8 av, hv;
        #pragma unroll
        for (int j = 0; j < 8; ++j) {
            av[j] = (f16)__expf(A[8 * q + j] * sdl);
            hv[j] = (f16)h[8 * q + j];
        }
        ap[q] = av; he[q] = hv;
    }
}

// ---------------------------------------------------------------------------
// K5: chunk-prefix over G=256 for each of 12288 sequences  [round-9 verbatim]
// ---------------------------------------------------------------------------
__global__ __launch_bounds__(256) void k5_prefix(
    const f16* __restrict__ aprod, const f16* __restrict__ hend,
    f16* __restrict__ hin)
{
    int s = blockIdx.x * 256 + threadIdx.x;
    float h = 0.f;
    #pragma unroll 8
    for (int g = 0; g < GG; ++g) {
        hin[(size_t)g * NSEQ + s] = (f16)h;
        h = (float)aprod[(size_t)g * NSEQ + s] * h + (float)hend[(size_t)g * NSEQ + s];
    }
}

// ---------------------------------------------------------------------------
// K6: scan pass 2 — replay chunk from h_in, y = sum_n h[n]*C[n], then gate:
// G = y * silu(x_act) -> bf16.  [round-9 k6 + round-7-proven gate fusion]
// ---------------------------------------------------------------------------
__global__ __launch_bounds__(128) void k6_scan2(
    const f16* __restrict__ u, const f16* __restrict__ delta,
    const f16* __restrict__ Bm, const f16* __restrict__ Cm,
    const float* __restrict__ A_log, const f16* __restrict__ hin,
    const f16* __restrict__ xact,
    short* __restrict__ G)
{
    __shared__ __align__(16) float sB[LC * 16];
    __shared__ __align__(16) float sC[LC * 16];
    int g = blockIdx.x, ib = blockIdx.y, i = ib >> 1;
    int d = threadIdx.x;
    {
        const f16x4* bsrc = (const f16x4*)(Bm + ((size_t)ib * LLEN + (size_t)g * LC) * NN);
        const f16x4* csrc = (const f16x4*)(Cm + ((size_t)ib * LLEN + (size_t)g * LC) * NN);
        if (d < 64) ((float4*)sB)[d] = to_f4(bsrc[d]);
        else ((float4*)sC)[d - 64] = to_f4(csrc[d - 64]);
    }
    float A[16], h[16];
    {
        const float4* al = (const float4*)(A_log + ((size_t)i * DI + d) * NN);
        #pragma unroll
        for (int q = 0; q < 4; ++q) {
            float4 v = al[q];
            A[4 * q] = -__expf(v.x); A[4 * q + 1] = -__expf(v.y);
            A[4 * q + 2] = -__expf(v.z); A[4 * q + 3] = -__expf(v.w);
        }
    }
    {
        size_t seq = ((size_t)ib * DI + d) * NN;
        const f16x8* hp = (const f16x8*)(hin + (size_t)g * NSEQ + seq);
        #pragma unroll
        for (int q = 0; q < 2; ++q) {
            f16x8 v = hp[q];
            #pragma unroll
            for (int j = 0; j < 8; ++j) h[8 * q + j] = (float)v[j];
        }
    }
    __syncthreads();
    size_t base = ((size_t)ib * LLEN + (size_t)g * LC) * DI + d;
    #pragma unroll 4
    for (int li = 0; li < LC; ++li) {
        float dl = (float)delta[base + li * DI];
        float du = dl * (float)u[base + li * DI];
        const float4* bl = (const float4*)(sB + li * 16);
        const float4* cl = (const float4*)(sC + li * 16);
        float4 b0 = bl[0], b1 = bl[1], b2 = bl[2], b3 = bl[3];
        float4 c0 = cl[0], c1 = cl[1], c2 = cl[2], c3 = cl[3];
        float acc = 0.f;
        h[0] = __expf(dl * A[0]) * h[0] + du * b0.x;  acc += h[0] * c0.x;
        h[1] = __expf(dl * A[1]) * h[1] + du * b0.y;  acc += h[1] * c0.y;
        h[2] = __expf(dl * A[2]) * h[2] + du * b0.z;  acc += h[2] * c0.z;
        h[3] = __expf(dl * A[3]) * h[3] + du * b0.w;  acc += h[3] * c0.w;
        h[4] = __expf(dl * A[4]) * h[4] + du * b1.x;  acc += h[4] * c1.x;
        h[5] = __expf(dl * A[5]) * h[5] + du * b1.y;  acc += h[5] * c1.y;
        h[6] = __expf(dl * A[6]) * h[6] + du * b1.z;  acc += h[6] * c1.z;
        h[7] = __expf(dl * A[7]) * h[7] + du * b1.w;  acc += h[7] * c1.w;
        h[8] = __expf(dl * A[8]) * h[8] + du * b2.x;  acc += h[8] * c2.x;
        h[9] = __expf(dl * A[9]) * h[9] + du * b2.y;  acc += h[9] * c2.y;
        h[10] = __expf(dl * A[10]) * h[10] + du * b2.z; acc += h[10] * c2.z;
        h[11] = __expf(dl * A[11]) * h[11] + du * b2.w; acc += h[11] * c2.w;
        h[12] = __expf(dl * A[12]) * h[12] + du * b3.x; acc += h[12] * c3.x;
        h[13] = __expf(dl * A[13]) * h[13] + du * b3.y; acc += h[13] * c3.y;
        h[14] = __expf(dl * A[14]) * h[14] + du * b3.z; acc += h[14] * c3.z;
        h[15] = __expf(dl * A[15]) * h[15] + du * b3.w; acc += h[15] * c3.w;
        float xa = (float)xact[base + li * DI];
        G[base + li * DI] = cvt_bf16(acc * siluf(xa));
    }
}

// ---------------------------------------------------------------------------
// K7 (MFMA): out-proj of pre-gated bf16 G, summed over branches, + residuals.
// grid (64 ltile, 2 b), 256 threads = 4 waves.  [round-7 verbatim]
// ---------------------------------------------------------------------------
__global__ __launch_bounds__(256) void k7_out(
    const short* __restrict__ G,
    const float* __restrict__ out_w,
    const float* __restrict__ fx, const float* __restrict__ fy, const float* __restrict__ fz,
    float* __restrict__ out)
{
    __shared__ short sG[64 * 128]; // [l][d] bf16, 16B-block XOR swizzle
    int lt = blockIdx.x, b = blockIdx.y;
    int l0 = lt * 64;
    int t = threadIdx.x;
    int w = t >> 6, lane = t & 63, lo = lane & 15, hi = lane >> 4;

    f32x4 acc[4];
    #pragma unroll
    for (int nt = 0; nt < 4; ++nt) acc[nt] = (f32x4){0.f, 0.f, 0.f, 0.f};

    for (int i = 0; i < 3; ++i) {
        size_t base = ((size_t)(i * 2 + b)) * DI * LLEN;
        __syncthreads();
        #pragma unroll
        for (int p = 0; p < 4; ++p) {
            int idx = t + 256 * p; // 1024 = 64 l x 16 blocks(8 d)
            int db = idx & 15, l = idx >> 4;
            bf16x8 v = *(const bf16x8*)&G[base + (size_t)(l0 + l) * DI + db * 8];
            int bs = (db & 8) | ((db ^ (l & 7)) & 7);
            *(bf16x8*)&sG[l * 128 + bs * 8] = v;
        }
        __syncthreads();

        const float* ow = out_w + (size_t)i * CC * DI;
        bf16x8 a[4];
        #pragma unroll
        for (int ks = 0; ks < 4; ++ks) {
            const float* ap = ow + (size_t)(16 * w + lo) * 128 + ks * 32 + hi * 8;
            a[ks] = pack8(*(const float4*)ap, *(const float4*)(ap + 4));
        }
        #pragma unroll
        for (int nt = 0; nt < 4; ++nt) {
            int l = 16 * nt + lo;
            #pragma unroll
            for (int ks = 0; ks < 4; ++ks) {
                int db = ks * 4 + hi;
                int bs = (db & 8) | ((db ^ (l & 7)) & 7);
                bf16x8 bv = *(const bf16x8*)&sG[l * 128 + bs * 8];
                acc[nt] = __builtin_amdgcn_mfma_f32_16x16x32_bf16(a[ks], bv, acc[nt], 0, 0, 0);
            }
        }
    }

    // epilogue: + residuals, write out[b][c][l]
    #pragma unroll
    for (int nt = 0; nt < 4; ++nt) {
        int l = l0 + 16 * nt + lo;
        int cbase = 16 * w + 4 * hi;
        #pragma unroll
        for (int rr = 0; rr < 4; ++rr) {
            int c = cbase + rr;
            size_t idx = ((size_t)b * CC + c) * LLEN + l;
            out[idx] = acc[nt][rr] + fx[idx] + fy[idx] + fz[idx];
        }
    }
}

} // namespace

extern "C" void kernel_launch(void* const* d_in, const int* in_sizes, int n_in,
                              void* d_out, int out_size, void* d_ws, size_t ws_size,
                              hipStream_t stream)
{
    (void)in_sizes; (void)n_in; (void)out_size; (void)ws_size;
    const float* up       = (const float*)d_in[0];
    const float* mask_    = (const float*)d_in[1];
    const float* fx       = (const float*)d_in[2];
    const float* fy       = (const float*)d_in[3];
    const float* fz       = (const float*)d_in[4];
    const float* pe_x_w   = (const float*)d_in[5];
    const float* pe_x_b   = (const float*)d_in[6];
    const float* rms_x_w  = (const float*)d_in[7];
    const float* conv_x_w = (const float*)d_in[8];
    const float* conv_x_b = (const float*)d_in[9];
    const float* pe_i_w   = (const float*)d_in[10];
    const float* pe_i_b   = (const float*)d_in[11];
    const float* rms_i_w  = (const float*)d_in[12];
    const float* conv_i_w = (const float*)d_in[13];
    const float* conv_i_b = (const float*)d_in[14];
    const float* pe_m_w   = (const float*)d_in[15];
    const float* pe_m_b   = (const float*)d_in[16];
    const float* rms_m_w  = (const float*)d_in[17];
    const float* conv_m_w = (const float*)d_in[18];
    const float* conv_m_b = (const float*)d_in[19];
    const float* in_x_w   = (const float*)d_in[20];
    const float* in_i_w   = (const float*)d_in[21];
    const float* in_m_w   = (const float*)d_in[22];
    const float* delta_w  = (const float*)d_in[23];
    const float* dt_w     = (const float*)d_in[24];
    const float* dt_b     = (const float*)d_in[25];
    const float* B_w      = (const float*)d_in[26];
    const float* C_w      = (const float*)d_in[27];
    const float* A_log    = (const float*)d_in[28];
    const float* out_w    = (const float*)d_in[29];
    float* out = (float*)d_out;

    // f16 workspace layout (slot = SBUF f16 elems = 6.3 MB) [round-9 verbatim]:
    f16* ws = (f16*)d_ws;
    const size_t S = SBUF;
    f16* xc_pre   = ws;          // dead after K3 -> hin
    f16* x_act    = ws + S;      // live until K6
    f16* info_pre = ws + 2 * S;  // dead after K3 -> aprod -> G
    f16* mk_pre   = ws + 3 * S;  // dead after K3 -> hend
    f16* ubuf     = ws + 4 * S;
    f16* dbuf     = ws + 5 * S;
    f16* BmB      = ws + 6 * S;
    f16* CmB      = BmB + (size_t)NB * BB * NN * LLEN;
    f16* aprod = info_pre;  // GG*NSEQ = 3145728 = S elems
    f16* hendb = mk_pre;
    f16* hinb  = xc_pre;
    short* Gbuf = (short*)info_pre; // overwrites aprod (dead after k5)

    hipLaunchKernelGGL(k1_embed, dim3(64, 9, 2), dim3(256), 0, stream,
        up, mask_, fx, fy, fz,
        pe_x_w, pe_x_b, rms_x_w, pe_i_w, pe_i_b, rms_i_w, pe_m_w, pe_m_b, rms_m_w,
        in_x_w, in_i_w, in_m_w, xc_pre, x_act, info_pre, mk_pre);

    hipLaunchKernelGGL(k3_conv, dim3(64, 6, 3), dim3(256), 0, stream,
        xc_pre, info_pre, mk_pre,
        conv_x_w, conv_x_b, conv_i_w, conv_i_b, conv_m_w, conv_m_b,
        delta_w, dt_w, dt_b, B_w, C_w, ubuf, dbuf, BmB, CmB);

    hipLaunchKernelGGL(k4_scan1, dim3(GG, 6), dim3(128), 0, stream,
        ubuf, dbuf, BmB, A_log, aprod, hendb);

    hipLaunchKernelGGL(k5_prefix, dim3(NSEQ / 256), dim3(256), 0, stream,
        aprod, hendb, hinb);

    hipLaunchKernelGGL(k6_scan2, dim3(GG, 6), dim3(128), 0, stream,
        ubuf, dbuf, BmB, CmB, A_log, hinb, x_act, Gbuf);

    hipLaunchKernelGGL(k7_out, dim3(64, 2), dim3(256), 0, stream,
        Gbuf, out_w, fx, fy, fz, out);
}